// Round 1
// baseline (1500.012 us; speedup 1.0000x reference)
//
#include <hip/hip_runtime.h>
#include <math.h>

// ---------------- problem constants ----------------
#define H_   12
#define NR_  512
#define NA_  256
#define N_   768
#define C1_  384
#define C2_  128
// SQK=16, PQK=4, SV=16, PV=8
static __device__ __constant__ float WC_  = 0.2357022603955158f;   // sqrt(2/(9*4))
static __device__ __constant__ float SC1_ = 0.14433756729740646f;  // sqrt(1/3)/sqrt(16)

// ---------------- workspace layout (float offsets) ----------------
// total 16,671,744 floats = 63.6 MiB — requires ws_size >= ~67 MB
#define OFF_Q1   0            // [768][12][16]
#define OFF_K1   147456       // [768][12][16]
#define OFF_V1   294912       // [768][12][16]
#define OFF_QP   442368       // [768][12][4][3]
#define OFF_KP   552960       // [768][12][4][3]
#define OFF_VP   663552       // [768][3][12][8]
#define OFF_R    884736       // [768][9]
#define OFF_T    891648       // [768][3]
#define OFF_BIAS 893952       // [768][768][12]
#define OFF_W    7971840      // [768][12][768]
#define OFF_FEAT 15049728     // [768][2112]

// ================= kernel A: per-token projections =================
__global__ __launch_bounds__(192) void proj_kernel(
    const float* __restrict__ rec_1d, const float* __restrict__ lig_1d,
    const float* __restrict__ rec_T,  const float* __restrict__ lig_T,
    const float* __restrict__ rec_w1d, const float* __restrict__ rec_wpt,
    const float* __restrict__ lig_w1d, const float* __restrict__ lig_wpt,
    float* __restrict__ ws) {
  const int tok0 = blockIdx.x * 4;
  const int tid  = threadIdx.x;       // 0..191
  __shared__ float xs[4][384];
  __shared__ float loc[4][576];
  __shared__ float Rs[4][9];
  __shared__ float tts[4][3];

  for (int r = 0; r < 4; ++r) {
    int n = tok0 + r;
    const float* x = (n < NR_) ? rec_1d + n * C1_ : lig_1d + (n - NR_) * C1_;
    for (int k = tid; k < C1_; k += 192) xs[r][k] = x[k];
  }
  if (tid < 4) {
    int n = tok0 + tid;
    const float* T = (n < NR_) ? rec_T + n * 7 : lig_T + (n - NR_) * 7;
    float qw = T[0], qx = T[1], qy = T[2], qz = T[3];
    float inv = 1.0f / sqrtf(qw*qw + qx*qx + qy*qy + qz*qz);
    qw *= inv; qx *= inv; qy *= inv; qz *= inv;
    Rs[tid][0] = 1.f - 2.f*(qy*qy + qz*qz);
    Rs[tid][1] = 2.f*(qx*qy - qw*qz);
    Rs[tid][2] = 2.f*(qx*qz + qw*qy);
    Rs[tid][3] = 2.f*(qx*qy + qw*qz);
    Rs[tid][4] = 1.f - 2.f*(qx*qx + qz*qz);
    Rs[tid][5] = 2.f*(qy*qz - qw*qx);
    Rs[tid][6] = 2.f*(qx*qz - qw*qy);
    Rs[tid][7] = 2.f*(qy*qz + qw*qx);
    Rs[tid][8] = 1.f - 2.f*(qx*qx + qy*qy);
    tts[tid][0] = T[4]; tts[tid][1] = T[5]; tts[tid][2] = T[6];
    float* Rg = ws + OFF_R + n * 9;
    #pragma unroll
    for (int k = 0; k < 9; ++k) Rg[k] = Rs[tid][k];
    float* tg = ws + OFF_T + n * 3;
    tg[0] = T[4]; tg[1] = T[5]; tg[2] = T[6];
  }
  __syncthreads();

  const float* w1 = (tok0 < NR_) ? rec_w1d : lig_w1d;
  const float* w2 = (tok0 < NR_) ? rec_wpt : lig_wpt;
  for (int cc = 0; cc < 3; ++cc) {
    int c = tid + cc * 192;
    float a0=0,a1=0,a2=0,a3=0,b0=0,b1=0,b2=0,b3=0;
    for (int k = 0; k < C1_; ++k) {
      float wv = w1[k * 576 + c];
      float wp = w2[k * 576 + c];
      float x0 = xs[0][k], x1 = xs[1][k], x2 = xs[2][k], x3 = xs[3][k];
      a0 += x0*wv; a1 += x1*wv; a2 += x2*wv; a3 += x3*wv;
      b0 += x0*wp; b1 += x1*wp; b2 += x2*wp; b3 += x3*wp;
    }
    loc[0][c]=b0; loc[1][c]=b1; loc[2][c]=b2; loc[3][c]=b3;
    int h = c / 48, e = c % 48;
    float av[4] = {a0,a1,a2,a3};
    for (int r = 0; r < 4; ++r) {
      int n = tok0 + r;
      if (e < 16)      ws[OFF_K1 + n*192 + h*16 + e]        = av[r];
      else if (e < 32) ws[OFF_Q1 + n*192 + h*16 + (e-16)]   = av[r];
      else             ws[OFF_V1 + n*192 + h*16 + (e-32)]   = av[r];
    }
  }
  __syncthreads();

  {
    int cp = tid;                 // 0..191
    int h = cp >> 4, e = cp & 15;
    for (int r = 0; r < 4; ++r) {
      int n = tok0 + r;
      float g[3];
      #pragma unroll
      for (int d = 0; d < 3; ++d)
        g[d] = Rs[r][d*3+0]*loc[r][cp] + Rs[r][d*3+1]*loc[r][192+cp]
             + Rs[r][d*3+2]*loc[r][384+cp] + tts[r][d];
      if (e < 4) {
        #pragma unroll
        for (int d = 0; d < 3; ++d) ws[OFF_KP + n*144 + h*12 + e*3 + d] = g[d];
      } else if (e < 8) {
        #pragma unroll
        for (int d = 0; d < 3; ++d) ws[OFF_QP + n*144 + h*12 + (e-4)*3 + d] = g[d];
      } else {
        #pragma unroll
        for (int d = 0; d < 3; ++d) ws[OFF_VP + n*288 + d*96 + h*8 + (e-8)] = g[d];
      }
    }
  }
}

// ================= kernel B: pair bias (one wave per (i,j)) =================
__global__ __launch_bounds__(256) void bias_kernel(
    const float* __restrict__ rep, const float* __restrict__ rr_w,
    const float* __restrict__ ll_w, const float* __restrict__ rl_w,
    const float* __restrict__ lr_w, float* __restrict__ bias) {
  int wave = (int)((blockIdx.x * 256 + threadIdx.x) >> 6);
  int lane = threadIdx.x & 63;
  int i = wave / N_, j = wave % N_;
  const float* W = (i < NR_) ? ((j < NR_) ? rr_w : rl_w)
                             : ((j < NR_) ? lr_w : ll_w);
  const float2 v = *(const float2*)(rep + ((size_t)(i*N_ + j)) * C2_ + 2*lane);
  const float* w0 = W + (2*lane) * H_;
  const float* w1 = W + (2*lane + 1) * H_;
  float acc[H_];
  #pragma unroll
  for (int h = 0; h < H_; ++h) acc[h] = v.x * w0[h] + v.y * w1[h];
  #pragma unroll
  for (int off = 32; off; off >>= 1) {
    #pragma unroll
    for (int h = 0; h < H_; ++h) acc[h] += __shfl_down(acc[h], off);
  }
  if (lane == 0) {
    float* dst = bias + ((size_t)i * N_ + j) * H_;
    #pragma unroll
    for (int h = 0; h < H_; ++h) dst[h] = acc[h];
  }
}

// ================= kernel C: affinity + softmax, per (i,h) =================
__global__ __launch_bounds__(256) void attn_kernel(float* __restrict__ ws) {
  const int i = blockIdx.x / H_;
  const int h = blockIdx.x % H_;
  const int tid = threadIdx.x;   // 256, each owns 3 j's
  const float* q1 = ws + OFF_Q1 + i*192 + h*16;
  const float* qp = ws + OFF_QP + i*144 + h*12;
  float q1v[16], qpv[12];
  #pragma unroll
  for (int c = 0; c < 16; ++c) q1v[c] = q1[c];
  #pragma unroll
  for (int c = 0; c < 12; ++c) qpv[c] = qp[c];

  float aff[3];
  #pragma unroll
  for (int r = 0; r < 3; ++r) {
    int j = tid + r*256;
    const float* kk = ws + OFF_K1 + j*192 + h*16;
    float s = 0.f;
    #pragma unroll
    for (int c = 0; c < 16; ++c) s += q1v[c] * kk[c];
    const float* kpp = ws + OFF_KP + j*144 + h*12;
    float d2 = 0.f;
    #pragma unroll
    for (int c = 0; c < 12; ++c) { float df = qpv[c] - kpp[c]; d2 += df*df; }
    aff[r] = ws[OFF_BIAS + ((size_t)i*N_ + j)*H_ + h] + SC1_*s - WC_*d2;
  }
  float m = fmaxf(fmaxf(aff[0], aff[1]), aff[2]);
  #pragma unroll
  for (int off = 32; off; off >>= 1) m = fmaxf(m, __shfl_xor(m, off));
  __shared__ float redm[4], reds[4];
  int wid = tid >> 6, lane = tid & 63;
  if (lane == 0) redm[wid] = m;
  __syncthreads();
  m = fmaxf(fmaxf(redm[0], redm[1]), fmaxf(redm[2], redm[3]));
  float e0 = __expf(aff[0]-m), e1 = __expf(aff[1]-m), e2 = __expf(aff[2]-m);
  float ssum = e0 + e1 + e2;
  #pragma unroll
  for (int off = 32; off; off >>= 1) ssum += __shfl_xor(ssum, off);
  if (lane == 0) reds[wid] = ssum;
  __syncthreads();
  float invs = 1.0f / (reds[0] + reds[1] + reds[2] + reds[3]);
  float* wo = ws + OFF_W + ((size_t)i*H_ + h) * N_;
  wo[tid      ] = e0 * invs;
  wo[tid + 256] = e1 * invs;
  wo[tid + 512] = e2 * invs;
}

// ================= kernel D: o_2d = sum_j w * rep_2d[i,j,:] =================
__global__ __launch_bounds__(256) void o2d_kernel(
    const float* __restrict__ rep, const float* __restrict__ w,
    float* __restrict__ feat) {
  const int i = blockIdx.x;
  const int tid = threadIdx.x;
  const int c = tid & 127, half = tid >> 7;
  __shared__ float wl[H_ * N_];     // 36 KB
  for (int k = tid; k < H_*N_; k += 256) wl[k] = w[(size_t)i*H_*N_ + k];
  __syncthreads();
  float acc[H_] = {0,0,0,0,0,0,0,0,0,0,0,0};
  const float* rrow = rep + (size_t)i * N_ * C2_;
  for (int j = half; j < N_; j += 2) {
    float val = rrow[j*C2_ + c];
    #pragma unroll
    for (int h = 0; h < H_; ++h) acc[h] += wl[h*N_ + j] * val;
  }
  __syncthreads();
  if (half == 1) {
    #pragma unroll
    for (int h = 0; h < H_; ++h) wl[h*128 + c] = acc[h];
  }
  __syncthreads();
  if (half == 0) {
    #pragma unroll
    for (int h = 0; h < H_; ++h)
      feat[(size_t)i*2112 + h*128 + c] = acc[h] + wl[h*128 + c];
  }
}

// ========= kernel E: point outputs + o_1d + o_pt + o_norm =========
__global__ __launch_bounds__(320) void opoint_kernel(
    const float* __restrict__ w, const float* __restrict__ vp,
    const float* __restrict__ R, const float* __restrict__ tvec,
    const float* __restrict__ v1, float* __restrict__ feat) {
  const int i = blockIdx.x;
  const int tid = threadIdx.x;   // 320, 288 active for points
  __shared__ float wl[H_ * N_];  // 36 KB
  __shared__ float og[288];
  __shared__ float ol[288];
  for (int k = tid; k < H_*N_; k += 320) wl[k] = w[(size_t)i*H_*N_ + k];
  __syncthreads();
  if (tid < 288) {
    int d = tid / 96, hh = (tid % 96) / 8;
    float acc = 0.f;
    for (int j = 0; j < N_; ++j) acc += wl[hh*N_ + j] * vp[(size_t)j*288 + tid];
    og[tid] = acc - tvec[i*3 + d];
  }
  if (tid < 192) feat[(size_t)i*2112 + 1536 + tid] = v1[(size_t)i*192 + tid];
  __syncthreads();
  if (tid < 288) {
    int i3 = tid / 96, rem = tid % 96, hh = rem / 8, p = rem % 8;
    float o = R[i*9 + 0*3 + i3] * og[0*96 + rem]
            + R[i*9 + 1*3 + i3] * og[1*96 + rem]
            + R[i*9 + 2*3 + i3] * og[2*96 + rem];
    ol[tid] = o;
    feat[(size_t)i*2112 + 1728 + p*36 + hh*3 + i3] = o;
  }
  __syncthreads();
  if (tid < 96) {
    int hh = tid / 8, p = tid % 8;
    float a = ol[0*96 + tid], b = ol[1*96 + tid], c = ol[2*96 + tid];
    feat[(size_t)i*2112 + 2016 + p*12 + hh] = sqrtf(a*a + b*b + c*c);
  }
}

// ================= kernel F: feat @ final_w + final_b =================
__global__ __launch_bounds__(384) void final_kernel(
    const float* __restrict__ ws, const float* __restrict__ fw,
    const float* __restrict__ fb, float* __restrict__ out) {
  const int i0 = blockIdx.x * 8;
  const int o  = threadIdx.x;    // 384
  __shared__ float fl[8 * 176];
  float acc[8] = {0,0,0,0,0,0,0,0};
  const float* feat = ws + OFF_FEAT;
  for (int f0 = 0; f0 < 2112; f0 += 176) {
    __syncthreads();
    for (int k = o; k < 8*176; k += 384) {
      int r = k / 176, f = k % 176;
      fl[k] = feat[(size_t)(i0 + r)*2112 + f0 + f];
    }
    __syncthreads();
    for (int f = 0; f < 176; ++f) {
      float wv = fw[(size_t)(f0 + f)*384 + o];
      #pragma unroll
      for (int r = 0; r < 8; ++r) acc[r] += fl[r*176 + f] * wv;
    }
  }
  float b = fb[o];
  #pragma unroll
  for (int r = 0; r < 8; ++r) out[(size_t)(i0 + r)*384 + o] = acc[r] + b;
}

// ================= launch =================
extern "C" void kernel_launch(void* const* d_in, const int* in_sizes, int n_in,
                              void* d_out, int out_size, void* d_ws, size_t ws_size,
                              hipStream_t stream) {
  const float* rec_1d  = (const float*)d_in[0];
  const float* lig_1d  = (const float*)d_in[1];
  const float* rep_2d  = (const float*)d_in[2];
  const float* rec_T   = (const float*)d_in[3];
  const float* lig_T   = (const float*)d_in[4];
  const float* rec_w1d = (const float*)d_in[5];
  const float* rec_wpt = (const float*)d_in[6];
  const float* lig_w1d = (const float*)d_in[7];
  const float* lig_wpt = (const float*)d_in[8];
  const float* rr_w    = (const float*)d_in[9];
  const float* ll_w    = (const float*)d_in[10];
  const float* rl_w    = (const float*)d_in[11];
  const float* lr_w    = (const float*)d_in[12];
  const float* final_w = (const float*)d_in[13];
  const float* final_b = (const float*)d_in[14];
  float* ws  = (float*)d_ws;
  float* out = (float*)d_out;

  proj_kernel<<<192, 192, 0, stream>>>(rec_1d, lig_1d, rec_T, lig_T,
                                       rec_w1d, rec_wpt, lig_w1d, lig_wpt, ws);
  bias_kernel<<<(N_*N_)/4, 256, 0, stream>>>(rep_2d, rr_w, ll_w, rl_w, lr_w,
                                             ws + OFF_BIAS);
  attn_kernel<<<N_*H_, 256, 0, stream>>>(ws);
  o2d_kernel<<<N_, 256, 0, stream>>>(rep_2d, ws + OFF_W, ws + OFF_FEAT);
  opoint_kernel<<<N_, 320, 0, stream>>>(ws + OFF_W, ws + OFF_VP, ws + OFF_R,
                                        ws + OFF_T, ws + OFF_V1, ws + OFF_FEAT);
  final_kernel<<<N_/8, 384, 0, stream>>>(ws, final_w, final_b, out);
}

// Round 2
// 863.850 us; speedup vs baseline: 1.7364x; 1.7364x over previous
//
#include <hip/hip_runtime.h>
#include <math.h>

// ---------------- problem constants ----------------
#define H_   12
#define NRR  512
#define N_   768
#define C1_  384
#define C2_  128
static __device__ __constant__ float WC_  = 0.2357022603955158f;   // sqrt(2/(9*4))
static __device__ __constant__ float SC1_ = 0.14433756729740646f;  // sqrt(1/3)/sqrt(16)

// ---------------- workspace layout (float offsets), total 40.9 MiB ----------------
#define OFF_Q1   0            // [768][12][16]
#define OFF_QP   147456       // [768][12][12]
#define OFF_V1   258048       // [768][12][16]
#define OFF_VP   405504       // [768][3][96]   ([j][d][h*8+p])
#define OFF_R    626688       // [768][9]
#define OFF_T    633600       // [768][3]
#define OFF_KHAT 635904       // [12][768][32]  (0..15 k1, 16..27 kp, 28..31 unused)
#define OFF_W    930816       // [768][12][768] bias, overwritten in-place with weights
#define OFF_FEAT 8008704      // [768][2112]
#define OFF_PART 9630720      // [2][768][384]

// ================= kernel A: per-token projections =================
__global__ __launch_bounds__(192) void proj_kernel(
    const float* __restrict__ rec_1d, const float* __restrict__ lig_1d,
    const float* __restrict__ rec_T,  const float* __restrict__ lig_T,
    const float* __restrict__ rec_w1d, const float* __restrict__ rec_wpt,
    const float* __restrict__ lig_w1d, const float* __restrict__ lig_wpt,
    float* __restrict__ ws) {
  const int tok0 = blockIdx.x * 4;
  const int tid  = threadIdx.x;       // 0..191
  __shared__ float xs[4][384];
  __shared__ float loc[4][576];
  __shared__ float Rs[4][9];
  __shared__ float tts[4][3];

  for (int r = 0; r < 4; ++r) {
    int n = tok0 + r;
    const float* x = (n < NRR) ? rec_1d + n * C1_ : lig_1d + (n - NRR) * C1_;
    for (int k = tid; k < C1_; k += 192) xs[r][k] = x[k];
  }
  if (tid < 4) {
    int n = tok0 + tid;
    const float* T = (n < NRR) ? rec_T + n * 7 : lig_T + (n - NRR) * 7;
    float qw = T[0], qx = T[1], qy = T[2], qz = T[3];
    float inv = 1.0f / sqrtf(qw*qw + qx*qx + qy*qy + qz*qz);
    qw *= inv; qx *= inv; qy *= inv; qz *= inv;
    Rs[tid][0] = 1.f - 2.f*(qy*qy + qz*qz);
    Rs[tid][1] = 2.f*(qx*qy - qw*qz);
    Rs[tid][2] = 2.f*(qx*qz + qw*qy);
    Rs[tid][3] = 2.f*(qx*qy + qw*qz);
    Rs[tid][4] = 1.f - 2.f*(qx*qx + qz*qz);
    Rs[tid][5] = 2.f*(qy*qz - qw*qx);
    Rs[tid][6] = 2.f*(qx*qz - qw*qy);
    Rs[tid][7] = 2.f*(qy*qz + qw*qx);
    Rs[tid][8] = 1.f - 2.f*(qx*qx + qy*qy);
    tts[tid][0] = T[4]; tts[tid][1] = T[5]; tts[tid][2] = T[6];
    float* Rg = ws + OFF_R + n * 9;
    #pragma unroll
    for (int k = 0; k < 9; ++k) Rg[k] = Rs[tid][k];
    float* tg = ws + OFF_T + n * 3;
    tg[0] = T[4]; tg[1] = T[5]; tg[2] = T[6];
  }
  __syncthreads();

  const float* w1 = (tok0 < NRR) ? rec_w1d : lig_w1d;
  const float* w2 = (tok0 < NRR) ? rec_wpt : lig_wpt;
  for (int cc = 0; cc < 3; ++cc) {
    int c = tid + cc * 192;
    float a0=0,a1=0,a2=0,a3=0,b0=0,b1=0,b2=0,b3=0;
    for (int k = 0; k < C1_; ++k) {
      float wv = w1[k * 576 + c];
      float wp = w2[k * 576 + c];
      float x0 = xs[0][k], x1 = xs[1][k], x2 = xs[2][k], x3 = xs[3][k];
      a0 += x0*wv; a1 += x1*wv; a2 += x2*wv; a3 += x3*wv;
      b0 += x0*wp; b1 += x1*wp; b2 += x2*wp; b3 += x3*wp;
    }
    loc[0][c]=b0; loc[1][c]=b1; loc[2][c]=b2; loc[3][c]=b3;
    int h = c / 48, e = c % 48;
    float av[4] = {a0,a1,a2,a3};
    for (int r = 0; r < 4; ++r) {
      int n = tok0 + r;
      if (e < 16)      ws[OFF_KHAT + ((size_t)h*N_ + n)*32 + e] = av[r];
      else if (e < 32) ws[OFF_Q1 + n*192 + h*16 + (e-16)]       = av[r];
      else             ws[OFF_V1 + n*192 + h*16 + (e-32)]       = av[r];
    }
  }
  __syncthreads();

  {
    int cp = tid;                 // 0..191
    int h = cp >> 4, e = cp & 15;
    for (int r = 0; r < 4; ++r) {
      int n = tok0 + r;
      float g[3];
      #pragma unroll
      for (int d = 0; d < 3; ++d)
        g[d] = Rs[r][d*3+0]*loc[r][cp] + Rs[r][d*3+1]*loc[r][192+cp]
             + Rs[r][d*3+2]*loc[r][384+cp] + tts[r][d];
      if (e < 4) {
        #pragma unroll
        for (int d = 0; d < 3; ++d)
          ws[OFF_KHAT + ((size_t)h*N_ + n)*32 + 16 + e*3 + d] = g[d];
      } else if (e < 8) {
        #pragma unroll
        for (int d = 0; d < 3; ++d) ws[OFF_QP + n*144 + h*12 + (e-4)*3 + d] = g[d];
      } else {
        #pragma unroll
        for (int d = 0; d < 3; ++d) ws[OFF_VP + n*288 + d*96 + h*8 + (e-8)] = g[d];
      }
    }
  }
}

// ================= kernel B: pair bias, LDS-tiled GEMV =================
// grid: 768*12 blocks; block handles (i, 64-j chunk), all 12 heads.
__global__ __launch_bounds__(256) void bias_kernel(
    const float* __restrict__ rep, const float* __restrict__ rr_w,
    const float* __restrict__ ll_w, const float* __restrict__ rl_w,
    const float* __restrict__ lr_w, float* __restrict__ wsW) {
  const int bx = blockIdx.x;
  const int i = bx / 12, jc = bx % 12;
  const int j0 = jc * 64;
  const int t = threadIdx.x;
  __shared__ float lds[64*128];   // swizzled rep tile, 32 KB
  __shared__ float wlw[12*128];   // W transposed [h][c], 6 KB
  const float* Wq = (i < NRR) ? ((j0 < NRR) ? rr_w : rl_w)
                              : ((j0 < NRR) ? lr_w : ll_w);
  for (int idx = t; idx < 1536; idx += 256) {
    int h = idx >> 7, c = idx & 127;
    wlw[idx] = Wq[c*12 + h];
  }
  const float* src = rep + ((size_t)i*N_ + j0) * C2_;
  for (int idx = t; idx < 2048; idx += 256) {
    int j = idx >> 5, c4 = idx & 31;
    float4 v = *(const float4*)(src + j*128 + c4*4);
    *(float4*)&lds[j*128 + ((c4 ^ j) & 31) * 4] = v;   // XOR swizzle (j<64 -> j&31 in xor)
  }
  __syncthreads();
  const int j = t & 63, hg = t >> 6;
  const int jx = j & 31;
  float a0 = 0.f, a1 = 0.f, a2 = 0.f;
  const float* w0p = wlw + hg*128;
  const float* w1p = wlw + (hg+4)*128;
  const float* w2p = wlw + (hg+8)*128;
  #pragma unroll 8
  for (int c4 = 0; c4 < 32; ++c4) {
    float4 d  = *(const float4*)&lds[j*128 + ((c4 ^ jx) << 2)];
    float4 w0 = *(const float4*)&w0p[c4*4];
    float4 w1 = *(const float4*)&w1p[c4*4];
    float4 w2 = *(const float4*)&w2p[c4*4];
    a0 += d.x*w0.x + d.y*w0.y + d.z*w0.z + d.w*w0.w;
    a1 += d.x*w1.x + d.y*w1.y + d.z*w1.z + d.w*w1.w;
    a2 += d.x*w2.x + d.y*w2.y + d.z*w2.z + d.w*w2.w;
  }
  wsW[((size_t)i*12 + hg    )*N_ + j0 + j] = a0;
  wsW[((size_t)i*12 + hg + 4)*N_ + j0 + j] = a1;
  wsW[((size_t)i*12 + hg + 8)*N_ + j0 + j] = a2;
}

// ================= kernel C: affinity + softmax, per (i,h) =================
// reads bias[i][h][j] from OFF_W and overwrites it in-place with weights.
__global__ __launch_bounds__(256) void attn_kernel(float* ws) {
  const int i = blockIdx.x / H_;
  const int h = blockIdx.x % H_;
  const int tid = threadIdx.x;   // 256, each owns 3 j's
  float q1v[16], qpv[12];
  #pragma unroll
  for (int c = 0; c < 16; c += 4)
    *(float4*)&q1v[c] = *(const float4*)(ws + OFF_Q1 + i*192 + h*16 + c);
  #pragma unroll
  for (int c = 0; c < 12; c += 4)
    *(float4*)&qpv[c] = *(const float4*)(ws + OFF_QP + i*144 + h*12 + c);

  float* wrow = ws + OFF_W + ((size_t)i*H_ + h) * N_;
  float aff[3];
  #pragma unroll
  for (int r = 0; r < 3; ++r) {
    int j = tid + r*256;
    const float* khf = ws + OFF_KHAT + ((size_t)h*N_ + j)*32;
    float kv[28];
    #pragma unroll
    for (int c = 0; c < 28; c += 4) *(float4*)&kv[c] = *(const float4*)(khf + c);
    float s = 0.f;
    #pragma unroll
    for (int c = 0; c < 16; ++c) s += q1v[c] * kv[c];
    float d2 = 0.f;
    #pragma unroll
    for (int c = 0; c < 12; ++c) { float df = qpv[c] - kv[16+c]; d2 += df*df; }
    aff[r] = wrow[j] + SC1_*s - WC_*d2;
  }
  float m = fmaxf(fmaxf(aff[0], aff[1]), aff[2]);
  #pragma unroll
  for (int off = 32; off; off >>= 1) m = fmaxf(m, __shfl_xor(m, off));
  __shared__ float redm[4], reds[4];
  int wid = tid >> 6, lane = tid & 63;
  if (lane == 0) redm[wid] = m;
  __syncthreads();
  m = fmaxf(fmaxf(redm[0], redm[1]), fmaxf(redm[2], redm[3]));
  float e0 = __expf(aff[0]-m), e1 = __expf(aff[1]-m), e2 = __expf(aff[2]-m);
  float ssum = e0 + e1 + e2;
  #pragma unroll
  for (int off = 32; off; off >>= 1) ssum += __shfl_xor(ssum, off);
  if (lane == 0) reds[wid] = ssum;
  __syncthreads();
  float invs = 1.0f / (reds[0] + reds[1] + reds[2] + reds[3]);
  wrow[tid      ] = e0 * invs;
  wrow[tid + 256] = e1 * invs;
  wrow[tid + 512] = e2 * invs;
}

// ================= kernel D: o_2d, register-blocked =================
// block per i; thread t: c4 = t&31 (4 channels), jg = t>>5 (j stride 8).
__global__ __launch_bounds__(256) void o2d_kernel(
    const float* __restrict__ rep, const float* __restrict__ w,
    float* __restrict__ feat) {
  const int i = blockIdx.x;
  const int t = threadIdx.x;
  __shared__ float wl[N_ * H_];   // [j][12], 36 KB (reused for reduction)
  for (int idx = t; idx < 2304; idx += 256) {   // 2304 float4 = 9216 floats
    float4 g = *(const float4*)(w + (size_t)i*9216 + idx*4);
    int h = idx / 192, j4 = idx % 192;
    wl[(j4*4+0)*12 + h] = g.x;
    wl[(j4*4+1)*12 + h] = g.y;
    wl[(j4*4+2)*12 + h] = g.z;
    wl[(j4*4+3)*12 + h] = g.w;
  }
  __syncthreads();
  const int c4 = t & 31, jg = t >> 5;
  float acc[48];
  #pragma unroll
  for (int k = 0; k < 48; ++k) acc[k] = 0.f;
  const float* rrow = rep + (size_t)i * N_ * C2_;
  #pragma unroll 4
  for (int j = jg; j < N_; j += 8) {
    float4 v = *(const float4*)(rrow + j*128 + c4*4);
    float4 wa = *(const float4*)&wl[j*12];
    float4 wb = *(const float4*)&wl[j*12 + 4];
    float4 wc = *(const float4*)&wl[j*12 + 8];
    float wv[12] = {wa.x,wa.y,wa.z,wa.w, wb.x,wb.y,wb.z,wb.w, wc.x,wc.y,wc.z,wc.w};
    #pragma unroll
    for (int hh = 0; hh < 12; ++hh) {
      acc[hh*4+0] += v.x*wv[hh];
      acc[hh*4+1] += v.y*wv[hh];
      acc[hh*4+2] += v.z*wv[hh];
      acc[hh*4+3] += v.w*wv[hh];
    }
  }
  // reduce 8 jg-partials: shfl halves, then LDS tree over waves
  #pragma unroll
  for (int k = 0; k < 48; ++k) acc[k] += __shfl_xor(acc[k], 32);
  const int wave = t >> 6, lane = t & 63;
  __syncthreads();
  if (wave >= 2 && lane < 32) {
    float* dst = wl + (wave-2)*1536 + lane*48;
    #pragma unroll
    for (int k = 0; k < 48; ++k) dst[k] = acc[k];
  }
  __syncthreads();
  if (wave < 2 && lane < 32) {
    const float* s2 = wl + wave*1536 + lane*48;
    #pragma unroll
    for (int k = 0; k < 48; ++k) acc[k] += s2[k];
  }
  __syncthreads();
  if (wave == 1 && lane < 32) {
    float* dst = wl + lane*48;
    #pragma unroll
    for (int k = 0; k < 48; ++k) dst[k] = acc[k];
  }
  __syncthreads();
  if (wave == 0 && lane < 32) {
    const float* s2 = wl + lane*48;
    #pragma unroll
    for (int k = 0; k < 48; ++k) acc[k] += s2[k];
    #pragma unroll
    for (int hh = 0; hh < 12; ++hh) {
      float4 r;
      r.x = acc[hh*4+0]; r.y = acc[hh*4+1]; r.z = acc[hh*4+2]; r.w = acc[hh*4+3];
      *(float4*)&feat[(size_t)i*2112 + hh*128 + lane*4] = r;
    }
  }
}

// ========= kernel E: point outputs + o_1d + o_pt + o_norm =========
__global__ __launch_bounds__(320) void opoint_kernel(
    const float* __restrict__ w, const float* __restrict__ vp,
    const float* __restrict__ R, const float* __restrict__ tvec,
    const float* __restrict__ v1, float* __restrict__ feat) {
  const int i = blockIdx.x;
  const int tid = threadIdx.x;   // 320, 288 active for points
  __shared__ float wl[H_ * N_];  // [h][j], 36 KB
  __shared__ float og[288];
  __shared__ float ol[288];
  for (int k = tid; k < H_*N_; k += 320) wl[k] = w[(size_t)i*H_*N_ + k];
  __syncthreads();
  if (tid < 288) {
    int d = tid / 96, hh = (tid % 96) / 8;
    float acc = 0.f;
    for (int j = 0; j < N_; ++j) acc += wl[hh*N_ + j] * vp[(size_t)j*288 + tid];
    og[tid] = acc - tvec[i*3 + d];
  }
  if (tid < 192) feat[(size_t)i*2112 + 1536 + tid] = v1[(size_t)i*192 + tid];
  __syncthreads();
  if (tid < 288) {
    int i3 = tid / 96, rem = tid % 96, hh = rem / 8, p = rem % 8;
    float o = R[i*9 + 0*3 + i3] * og[0*96 + rem]
            + R[i*9 + 1*3 + i3] * og[1*96 + rem]
            + R[i*9 + 2*3 + i3] * og[2*96 + rem];
    ol[tid] = o;
    feat[(size_t)i*2112 + 1728 + p*36 + hh*3 + i3] = o;
  }
  __syncthreads();
  if (tid < 96) {
    int hh = tid / 8, p = tid % 8;
    float a = ol[0*96 + tid], b = ol[1*96 + tid], c = ol[2*96 + tid];
    feat[(size_t)i*2112 + 2016 + p*12 + hh] = sqrtf(a*a + b*b + c*c);
  }
}

// ================= kernel F1: feat @ final_w partials (k-split x2) =================
__global__ __launch_bounds__(384) void final1_kernel(
    const float* __restrict__ ws, const float* __restrict__ fw,
    float* __restrict__ part) {
  const int i0 = blockIdx.x * 4;
  const int ks = blockIdx.y;
  const int o  = threadIdx.x;    // 384
  const int k0 = ks * 1056;
  __shared__ float fl[4 * 1056]; // 16.5 KB
  const float* feat = ws + OFF_FEAT;
  for (int idx = o; idx < 1056; idx += 384) {   // 1056 float4 = 4224 floats
    int r = idx / 264, f4 = idx % 264;
    *(float4*)&fl[r*1056 + f4*4] =
        *(const float4*)(feat + (size_t)(i0+r)*2112 + k0 + f4*4);
  }
  __syncthreads();
  float a0=0,a1=0,a2=0,a3=0;
  for (int f4 = 0; f4 < 264; ++f4) {
    int f = k0 + f4*4;
    float w0 = fw[(size_t)(f+0)*384 + o];
    float w1 = fw[(size_t)(f+1)*384 + o];
    float w2 = fw[(size_t)(f+2)*384 + o];
    float w3 = fw[(size_t)(f+3)*384 + o];
    float4 f0 = *(const float4*)&fl[0*1056 + f4*4];
    float4 f1 = *(const float4*)&fl[1*1056 + f4*4];
    float4 f2 = *(const float4*)&fl[2*1056 + f4*4];
    float4 f3 = *(const float4*)&fl[3*1056 + f4*4];
    a0 += f0.x*w0 + f0.y*w1 + f0.z*w2 + f0.w*w3;
    a1 += f1.x*w0 + f1.y*w1 + f1.z*w2 + f1.w*w3;
    a2 += f2.x*w0 + f2.y*w1 + f2.z*w2 + f2.w*w3;
    a3 += f3.x*w0 + f3.y*w1 + f3.z*w2 + f3.w*w3;
  }
  part[((size_t)ks*N_ + i0+0)*384 + o] = a0;
  part[((size_t)ks*N_ + i0+1)*384 + o] = a1;
  part[((size_t)ks*N_ + i0+2)*384 + o] = a2;
  part[((size_t)ks*N_ + i0+3)*384 + o] = a3;
}

// ================= kernel F2: add partials + bias =================
__global__ __launch_bounds__(256) void final2_kernel(
    const float* __restrict__ part, const float* __restrict__ fb,
    float* __restrict__ out) {
  int idx = blockIdx.x * 256 + threadIdx.x;   // < 294912
  int col = idx % 384;
  out[idx] = part[idx] + part[294912 + idx] + fb[col];
}

// ================= launch =================
extern "C" void kernel_launch(void* const* d_in, const int* in_sizes, int n_in,
                              void* d_out, int out_size, void* d_ws, size_t ws_size,
                              hipStream_t stream) {
  const float* rec_1d  = (const float*)d_in[0];
  const float* lig_1d  = (const float*)d_in[1];
  const float* rep_2d  = (const float*)d_in[2];
  const float* rec_T   = (const float*)d_in[3];
  const float* lig_T   = (const float*)d_in[4];
  const float* rec_w1d = (const float*)d_in[5];
  const float* rec_wpt = (const float*)d_in[6];
  const float* lig_w1d = (const float*)d_in[7];
  const float* lig_wpt = (const float*)d_in[8];
  const float* rr_w    = (const float*)d_in[9];
  const float* ll_w    = (const float*)d_in[10];
  const float* rl_w    = (const float*)d_in[11];
  const float* lr_w    = (const float*)d_in[12];
  const float* final_w = (const float*)d_in[13];
  const float* final_b = (const float*)d_in[14];
  float* ws  = (float*)d_ws;
  float* out = (float*)d_out;

  proj_kernel<<<192, 192, 0, stream>>>(rec_1d, lig_1d, rec_T, lig_T,
                                       rec_w1d, rec_wpt, lig_w1d, lig_wpt, ws);
  bias_kernel<<<N_*12, 256, 0, stream>>>(rep_2d, rr_w, ll_w, rl_w, lr_w,
                                         ws + OFF_W);
  attn_kernel<<<N_*H_, 256, 0, stream>>>(ws);
  o2d_kernel<<<N_, 256, 0, stream>>>(rep_2d, ws + OFF_W, ws + OFF_FEAT);
  opoint_kernel<<<N_, 320, 0, stream>>>(ws + OFF_W, ws + OFF_VP, ws + OFF_R,
                                        ws + OFF_T, ws + OFF_V1, ws + OFF_FEAT);
  final1_kernel<<<dim3(N_/4, 2), 384, 0, stream>>>(ws, final_w, ws + OFF_PART);
  final2_kernel<<<1152, 256, 0, stream>>>(ws + OFF_PART, final_b, out);
}